// Round 2
// baseline (549.541 us; speedup 1.0000x reference)
//
#include <hip/hip_runtime.h>

#define POOLED 14
#define NPOS   196      // 14*14
#define NCH    256
#define NQUAD  49       // 196/4

typedef float f2a __attribute__((ext_vector_type(2), aligned(4)));  // dword-aligned pair load
typedef float f4  __attribute__((ext_vector_type(4)));

// One block per roi. Phase 1: 196 threads compute per-position bilinear row-pair
// offsets + 4 weights into LDS (permuted: position p -> slot (p&3)*49 + (p>>2),
// so phase-2 reads are linear stride-16B -> conflict-free ds_read_b128).
// Phase 2: 49 iters x 256 threads; thread = (channel c, quad q); two dwordx2
// gathers per position (x-pair within a row); one coalesced nontemporal float4
// store per thread-iter. Output offset is exactly 4*idx -> linear.
__global__ __launch_bounds__(256)
void rroi_align_kernel(const float* __restrict__ f0, const float* __restrict__ f1,
                       const float* __restrict__ f2, const float* __restrict__ f3,
                       const float* __restrict__ b0, const float* __restrict__ b1,
                       const float* __restrict__ b2, const float* __restrict__ b3,
                       float* __restrict__ out)
{
    __shared__ f4   s_w[NPOS];
    __shared__ int2 s_o[NPOS];

    const int blk = blockIdx.x;        // 0..2047  (level*512 + roi)
    const int level = blk >> 9;
    const int roi = blk & 511;
    const int tid = threadIdx.x;

    const float* feat; const float* box; int H; int W; float scale;
    switch (level) {
      case 0:  feat = f0; box = b0; H = 200; W = 176; scale = 1.0f;    break;
      case 1:  feat = f1; box = b1; H = 100; W = 88;  scale = 0.5f;    break;
      case 2:  feat = f2; box = b2; H = 50;  W = 44;  scale = 0.25f;   break;
      default: feat = f3; box = b3; H = 25;  W = 22;  scale = 0.125f;  break;
    }

    if (tid < NPOS) {
        const float* bp = box + roi * 7;
        const float bx = bp[0], by = bp[1], bw = bp[3], bl = bp[4], ry = bp[6];

        // _convert_boxes (mirror reference op order), then *scale (angle NOT scaled)
        const float cx = (bx * 175.0f / 70.4f + 0.5f) * scale;
        const float cy = ((by + 40.0f) * 199.0f / 80.0f + 0.5f) * scale;
        const float rw = (bw * 175.0f / 70.4f) * scale;
        const float rh = (bl * 199.0f / 80.0f) * scale;
        const float cth = cosf(ry), sth = sinf(ry);

        const int ph = tid / POOLED;
        const int pw = tid - ph * POOLED;
        const float fw = ((float)pw + 0.5f) / (float)POOLED - 0.5f;
        const float fh = ((float)ph + 0.5f) / (float)POOLED - 0.5f;
        const float lx = fw * rw;
        const float ly = fh * rh;
        const float x = cx + lx * cth - ly * sth;
        const float y = cy + lx * sth + ly * cth;

        const bool valid = (y > -1.0f) & (y < (float)H) & (x > -1.0f) & (x < (float)W);
        const float yc = fminf(fmaxf(y, 0.0f), (float)(H - 1));
        const float xc = fminf(fmaxf(x, 0.0f), (float)(W - 1));
        const int y0 = (int)floorf(yc);
        const int x0 = (int)floorf(xc);
        const int y1 = min(y0 + 1, H - 1);
        const float dy = yc - (float)y0;
        const float dx = xc - (float)x0;
        const float hy = 1.0f - dy, hx = 1.0f - dx;

        float w00 = hy * hx, w01 = hy * dx, w10 = dy * hx, w11 = dy * dx;
        if (!valid) { w00 = 0.0f; w01 = 0.0f; w10 = 0.0f; w11 = 0.0f; }

        // x-pair base: load columns (xb, xb+1). If x0==W-1 (only when xc==W-1,
        // so dx==0), shift base left and swap weights: (0,hy,0,dy) on (W-2,W-1).
        const int xb = min(x0, W - 2);
        if (x0 == W - 1) {
            float t;
            t = w00; w00 = w01; w01 = t;
            t = w10; w10 = w11; w11 = t;
        }

        // permute: position p stored at slot (p&3)*49 + (p>>2)
        const int slot = (tid & 3) * NQUAD + (tid >> 2);
        s_w[slot] = (f4){w00, w01, w10, w11};
        s_o[slot] = make_int2(y0 * W + xb, y1 * W + xb);
    }
    __syncthreads();

    const int HW  = H * W;
    const int HW5 = 5 * HW, HW6 = 6 * HW;

    // idx = it*256 + tid; c = idx/49, q = idx%49; out offset = 4*idx (exact).
    int c = tid / NQUAD;
    int q = tid - c * NQUAD;
    const float* __restrict__ fc = feat + c * HW;
    float* po = out + (size_t)blk * (NCH * NPOS) + tid * 4;

    #pragma unroll 1
    for (int it = 0; it < NQUAD; ++it) {
        f4 r;
        {
            const f4 w = s_w[q];                 const int2 o = s_o[q];
            const f2a a = *(const f2a*)(fc + o.x);
            const f2a b = *(const f2a*)(fc + o.y);
            r.x = a.x * w.x + a.y * w.y + b.x * w.z + b.y * w.w;
        }
        {
            const f4 w = s_w[NQUAD + q];         const int2 o = s_o[NQUAD + q];
            const f2a a = *(const f2a*)(fc + o.x);
            const f2a b = *(const f2a*)(fc + o.y);
            r.y = a.x * w.x + a.y * w.y + b.x * w.z + b.y * w.w;
        }
        {
            const f4 w = s_w[2 * NQUAD + q];     const int2 o = s_o[2 * NQUAD + q];
            const f2a a = *(const f2a*)(fc + o.x);
            const f2a b = *(const f2a*)(fc + o.y);
            r.z = a.x * w.x + a.y * w.y + b.x * w.z + b.y * w.w;
        }
        {
            const f4 w = s_w[3 * NQUAD + q];     const int2 o = s_o[3 * NQUAD + q];
            const f2a a = *(const f2a*)(fc + o.x);
            const f2a b = *(const f2a*)(fc + o.y);
            r.w = a.x * w.x + a.y * w.y + b.x * w.z + b.y * w.w;
        }
        __builtin_nontemporal_store(r, (f4*)po);

        // advance idx by 256: c += 5 (+1 on q wrap), q += 11 mod 49
        q += 11;
        int step = HW5;
        if (q >= NQUAD) { q -= NQUAD; step = HW6; }
        fc += step;
        po += 1024;
    }
}

extern "C" void kernel_launch(void* const* d_in, const int* in_sizes, int n_in,
                              void* d_out, int out_size, void* d_ws, size_t ws_size,
                              hipStream_t stream)
{
    const float* f0 = (const float*)d_in[0];
    const float* f1 = (const float*)d_in[1];
    const float* f2 = (const float*)d_in[2];
    const float* f3 = (const float*)d_in[3];
    const float* b0 = (const float*)d_in[4];
    const float* b1 = (const float*)d_in[5];
    const float* b2 = (const float*)d_in[6];
    const float* b3 = (const float*)d_in[7];
    float* out = (float*)d_out;

    rroi_align_kernel<<<2048, 256, 0, stream>>>(f0, f1, f2, f3, b0, b1, b2, b3, out);
}

// Round 4
// 539.961 us; speedup vs baseline: 1.0177x; 1.0177x over previous
//
#include <hip/hip_runtime.h>

#define POOLED 14
#define NPOS   196      // 14*14
#define NQUAD  49       // 196/4
#define SF_CAP 9216     // worst case G*SP <= ~7400 (level 0), + margin
#define META_N 200      // 196 padded for XOR swizzle range

typedef float f4 __attribute__((ext_vector_type(4)));

// metadata slot bank-group swizzle: breaks the stride-784B residue pattern
__device__ __forceinline__ int swz(int s) { return s ^ ((s >> 3) & 7); }

// One block per roi. Stage the roi's clipped bbox into LDS in channel-group
// passes (G=16<<level channels/pass), gather bilinear taps from LDS.
// Metadata per pooled position: {dx, A=hy*m, B=dy*m, u16x2 row offsets};
// border x0==W-1 encoded as dx=1.0, invalid sample as A=B=0.
__global__ __launch_bounds__(256)
void rroi_align_kernel(const float* __restrict__ f0, const float* __restrict__ f1,
                       const float* __restrict__ f2, const float* __restrict__ f3,
                       const float* __restrict__ b0, const float* __restrict__ b1,
                       const float* __restrict__ b2, const float* __restrict__ b3,
                       float* __restrict__ out)
{
    __shared__ float s_f[SF_CAP];
    __shared__ f4    s_meta[META_N];   // base slot = (p&3)*49 + (p>>2), then swz()

    const int blk = blockIdx.x;      // 0..2047 (level*512 + roi)
    const int level = blk >> 9;
    const int roi = blk & 511;
    const int tid = threadIdx.x;

    const float* feat; const float* box; int H; int W; float scale;
    switch (level) {
      case 0:  feat = f0; box = b0; H = 200; W = 176; scale = 1.0f;    break;
      case 1:  feat = f1; box = b1; H = 100; W = 88;  scale = 0.5f;    break;
      case 2:  feat = f2; box = b2; H = 50;  W = 44;  scale = 0.25f;   break;
      default: feat = f3; box = b3; H = 25;  W = 22;  scale = 0.125f;  break;
    }
    const int G     = 16 << level;   // channels per pass
    const int NPASS = 16 >> level;
    const int HW    = H * W;

    // ---- block-uniform box + clipped bbox ----
    const float* bp = box + roi * 7;
    const float cx  = (bp[0] * 175.0f / 70.4f + 0.5f) * scale;
    const float cy  = ((bp[1] + 40.0f) * 199.0f / 80.0f + 0.5f) * scale;
    const float rw  = (bp[3] * 175.0f / 70.4f) * scale;
    const float rh  = (bp[4] * 199.0f / 80.0f) * scale;
    const float cth = cosf(bp[6]), sth = sinf(bp[6]);

    const float ex = 0.5f * (fabsf(rw * cth) + fabsf(rh * sth));
    const float ey = 0.5f * (fabsf(rw * sth) + fabsf(rh * cth));
    const int Xlo = min(max((int)floorf(cx - ex), 0), W - 2);
    const int Xhi = min(W - 1, max((int)floorf(cx + ex) + 1, Xlo + 1));
    const int Ylo = min(max((int)floorf(cy - ey), 0), H - 1);
    const int Yhi = min(H - 1, max((int)floorf(cy + ey) + 1, Ylo + 1));
    const int bw = Xhi - Xlo + 1;          // <= ~22 at level 0
    const int bh = Yhi - Ylo + 1;
    const int SP = bw * bh;                // <= ~461; G*SP <= ~7400

    // magic divisors (exactness: el*e < 2^32 since el<=7744, e<=SP<=461;
    // rem*e2 < 2^18 since rem<SP<=461, e2<=bw<=23)
    const unsigned M1 = (unsigned)(4294967296.0 / (double)SP) + 1u;  // /SP
    const unsigned M2 = 262144u / (unsigned)bw + 1u;                 // /bw (2^18)

    // ---- phase 1: per-position metadata ----
    if (tid < NPOS) {
        const int ph = tid / POOLED;
        const int pw = tid - ph * POOLED;
        const float fwx = ((float)pw + 0.5f) / (float)POOLED - 0.5f;
        const float fhy = ((float)ph + 0.5f) / (float)POOLED - 0.5f;
        const float lx = fwx * rw;
        const float ly = fhy * rh;
        const float x = cx + lx * cth - ly * sth;
        const float y = cy + lx * sth + ly * cth;

        const bool valid = (y > -1.0f) & (y < (float)H) & (x > -1.0f) & (x < (float)W);
        const float yc = fminf(fmaxf(y, 0.0f), (float)(H - 1));
        const float xc = fminf(fmaxf(x, 0.0f), (float)(W - 1));
        const int y0 = (int)floorf(yc);
        const int x0 = (int)floorf(xc);
        const int y1 = min(y0 + 1, H - 1);
        const float dyw = yc - (float)y0;
        float dxw = xc - (float)x0;

        const float m = valid ? 1.0f : 0.0f;
        const float A = (1.0f - dyw) * m;    // top-row weight
        const float B = dyw * m;             // bottom-row weight

        int xb = x0;
        if (x0 == W - 1) { xb = W - 2; dxw = 1.0f; }  // dup-column border case

        const unsigned o0 = (unsigned)((y0 - Ylo) * bw + (xb - Xlo));
        const unsigned o1 = (unsigned)((y1 - Ylo) * bw + (xb - Xlo));
        const int slot = (tid & 3) * NQUAD + (tid >> 2);
        s_meta[swz(slot)] = (f4){dxw, A, B, __uint_as_float(o0 | (o1 << 16))};
    }

    float* const out_roi = out + (size_t)blk * (256 * NPOS);
    const int GITER = (G * NQUAD + 255) >> 8;

    for (int pass = 0; pass < NPASS; ++pass) {
        const int cbase = pass * G;
        const float* __restrict__ fpass = feat + (size_t)cbase * HW;

        // ---- stage G channels' bbox into LDS (coalesced row segments) ----
        const int E = G * SP;
        for (int el = tid; el < E; el += 256) {
            const int g   = (int)__umulhi((unsigned)el, M1);   // el / SP
            const int rem = el - g * SP;
            const int ry  = (int)(((unsigned)rem * M2) >> 18); // rem / bw
            const int rx  = rem - ry * bw;
            s_f[el] = fpass[g * HW + (Ylo + ry) * W + (Xlo + rx)];
        }
        __syncthreads();   // also covers phase-1 s_meta on pass 0

        // ---- gather: task t = (c_local, quad q); 4 positions -> float4 ----
        const int TMAX = G * NQUAD;
        #pragma unroll 1
        for (int it = 0; it < GITER; ++it) {
            const int t = it * 256 + tid;
            if (t < TMAX) {
                const int c = t / NQUAD;
                const int q = t - c * NQUAD;
                const float* __restrict__ fb = s_f + c * SP;
                f4 r;
                #pragma unroll
                for (int j = 0; j < 4; ++j) {
                    const f4 md = s_meta[swz(j * NQUAD + q)];
                    const float dxw = md.x, A = md.y, B = md.z;
                    const unsigned pk = __float_as_uint(md.w);
                    const int o0 = (int)(pk & 0xffffu);
                    const int o1 = (int)(pk >> 16);
                    const float hx = 1.0f - dxw;
                    const float t0 = fb[o0], t1 = fb[o0 + 1];
                    const float u0 = fb[o1], u1 = fb[o1 + 1];
                    r[j] = A * (t0 * hx + t1 * dxw) + B * (u0 * hx + u1 * dxw);
                }
                // out offset = (cbase+c)*196 + 4q = 4*(cbase*49 + t)  -> linear
                __builtin_nontemporal_store(r, (f4*)(out_roi + (size_t)4 * (cbase * NQUAD + t)));
            }
        }
        __syncthreads();   // s_f reused next pass
    }
}

extern "C" void kernel_launch(void* const* d_in, const int* in_sizes, int n_in,
                              void* d_out, int out_size, void* d_ws, size_t ws_size,
                              hipStream_t stream)
{
    const float* f0 = (const float*)d_in[0];
    const float* f1 = (const float*)d_in[1];
    const float* f2 = (const float*)d_in[2];
    const float* f3 = (const float*)d_in[3];
    const float* b0 = (const float*)d_in[4];
    const float* b1 = (const float*)d_in[5];
    const float* b2 = (const float*)d_in[6];
    const float* b3 = (const float*)d_in[7];
    float* out = (float*)d_out;

    rroi_align_kernel<<<2048, 256, 0, stream>>>(f0, f1, f2, f3, b0, b1, b2, b3, out);
}

// Round 7
// 491.516 us; speedup vs baseline: 1.1181x; 1.0986x over previous
//
#include <hip/hip_runtime.h>

#define POOLED 14
#define NPOS   196
#define NQUAD  49
#define BUF_N  4096   // floats per staging buffer; MUST be multiple of 256:
                      // stage writes KMAX*256 lane-slots (clamped source,
                      // linear dest) -> tail overshoot stays inside buffer.

typedef float f4 __attribute__((ext_vector_type(4)));
typedef __attribute__((address_space(1))) const unsigned int guint;
typedef __attribute__((address_space(3))) unsigned int       luint;

// One block per roi. Channel-group passes (G adaptive, pow2, G*SP<=BUF_N).
// Staging: async global_load_lds (per-lane global src, linear LDS dest),
// double-buffered: stage(k+1) issued before gather(k); the compiler's
// vmcnt(0) drain at __syncthreads is the wait for stage(k).
// Gather: thread owns quad q=tid%49 (4 pooled positions) with metadata in
// registers; loops channels; 1 nontemporal dwordx4 store per task.
__global__ __launch_bounds__(256, 4)
void rroi_align_kernel(const float* __restrict__ f0, const float* __restrict__ f1,
                       const float* __restrict__ f2, const float* __restrict__ f3,
                       const float* __restrict__ b0, const float* __restrict__ b1,
                       const float* __restrict__ b2, const float* __restrict__ b3,
                       float* __restrict__ out)
{
    __shared__ float s_f[2][BUF_N];

    const int blk = blockIdx.x;      // 0..2047 (level*512 + roi)
    const int level = blk >> 9;
    const int roi = blk & 511;
    const int tid = threadIdx.x;

    const float* feat; const float* box; int H, W; float scale;
    switch (level) {
      case 0:  feat = f0; box = b0; H = 200; W = 176; scale = 1.0f;    break;
      case 1:  feat = f1; box = b1; H = 100; W = 88;  scale = 0.5f;    break;
      case 2:  feat = f2; box = b2; H = 50;  W = 44;  scale = 0.25f;   break;
      default: feat = f3; box = b3; H = 25;  W = 22;  scale = 0.125f;  break;
    }
    const int HW = H * W;

    // ---- block-uniform box + clipped bbox (identical math to passing R4) ----
    const float* bp = box + roi * 7;
    const float cx  = (bp[0] * 175.0f / 70.4f + 0.5f) * scale;
    const float cy  = ((bp[1] + 40.0f) * 199.0f / 80.0f + 0.5f) * scale;
    const float rw  = (bp[3] * 175.0f / 70.4f) * scale;
    const float rh  = (bp[4] * 199.0f / 80.0f) * scale;
    const float cth = cosf(bp[6]), sth = sinf(bp[6]);

    const float ex = 0.5f * (fabsf(rw * cth) + fabsf(rh * sth));
    const float ey = 0.5f * (fabsf(rw * sth) + fabsf(rh * cth));
    const int Xlo = min(max((int)floorf(cx - ex), 0), W - 2);
    const int Xhi = min(W - 1, max((int)floorf(cx + ex) + 1, Xlo + 1));
    const int Ylo = min(max((int)floorf(cy - ey), 0), H - 1);
    const int Yhi = min(H - 1, max((int)floorf(cy + ey) + 1, Ylo + 1));
    const int bw = Xhi - Xlo + 1;          // <= 22
    const int bh = Yhi - Ylo + 1;
    const int SP = bw * bh;                // <= 484

    // G = largest pow2 with G*SP <= BUF_N (>=8), clamp 256; NPASS = 256/G
    int Graw = BUF_N / SP;
    int G = 1 << (31 - __clz(Graw));
    if (G > 256) G = 256;
    const int NPASS = 256 / G;
    const int E     = G * SP;              // <= BUF_N
    const int KMAX  = (E + 255) >> 8;      // <= 16; KMAX*256 <= BUF_N (pow2 pad)
    const int GITER = (G + 4) / 5;

    // magic divisors (exact: els<=4095,SP<=484; rem<=483,bw in [2,23])
    const unsigned M1 = (unsigned)(4294967296.0 / (double)SP) + 1u;  // /SP
    const unsigned M2 = 262144u / (unsigned)bw + 1u;                 // /bw

    // ---- per-thread metadata in registers: quad q, positions 4q..4q+3 ----
    const int q  = tid % NQUAD;            // tids>=245 duplicate q, masked below
    const int cg = tid / NQUAD;            // 0..5
    const bool gok = (cg < 5);

    f4 md[4];
    #pragma unroll
    for (int j = 0; j < 4; ++j) {
        const int p  = q * 4 + j;
        const int ph = p / POOLED;
        const int pw = p - ph * POOLED;
        const float fwx = ((float)pw + 0.5f) / (float)POOLED - 0.5f;
        const float fhy = ((float)ph + 0.5f) / (float)POOLED - 0.5f;
        const float lx = fwx * rw;
        const float ly = fhy * rh;
        const float x = cx + lx * cth - ly * sth;
        const float y = cy + lx * sth + ly * cth;

        const bool valid = (y > -1.0f) & (y < (float)H) & (x > -1.0f) & (x < (float)W);
        const float yc = fminf(fmaxf(y, 0.0f), (float)(H - 1));
        const float xc = fminf(fmaxf(x, 0.0f), (float)(W - 1));
        const int y0 = (int)floorf(yc);
        const int x0 = (int)floorf(xc);
        const int y1 = min(y0 + 1, H - 1);
        const float dyw = yc - (float)y0;
        float dxw = xc - (float)x0;

        const float m = valid ? 1.0f : 0.0f;
        const float A = (1.0f - dyw) * m;   // top-row weight
        const float B = dyw * m;            // bottom-row weight

        int xb = x0;
        if (x0 == W - 1) { xb = W - 2; dxw = 1.0f; }   // dup-column border

        const unsigned o0 = (unsigned)((y0 - Ylo) * bw + (xb - Xlo));
        const unsigned o1 = (unsigned)((y1 - Ylo) * bw + (xb - Xlo));
        md[j] = (f4){dxw, A, B, __uint_as_float(o0 | (o1 << 16))};
    }

    const int wbase = tid & 192;           // wave base (0,64,128,192)
    const int lane  = tid & 63;

    // async stage of pass `pass` into buffer `bsel` (no waits issued here)
    auto stage = [&](int pass, int bsel) {
        const float* __restrict__ fp = feat + (size_t)(pass * G) * HW;
        for (int j = 0; j < KMAX; ++j) {
            int el = j * 256 + wbase + lane;
            int els = min(el, E - 1);                       // clamp SOURCE only
            int g   = (int)__umulhi((unsigned)els, M1);     // els / SP
            int rem = els - g * SP;
            int ry  = (int)(((unsigned)rem * M2) >> 18);    // rem / bw
            int rx  = rem - ry * bw;
            const float* src = fp + g * HW + (Ylo + ry) * W + (Xlo + rx);
            __builtin_amdgcn_global_load_lds((guint*)src,
                (luint*)&s_f[bsel][j * 256 + wbase], 4, 0, 0);
        }
    };

    float* const out_roi = out + (size_t)blk * (256 * NPOS);

    stage(0, 0);
    #pragma unroll 1
    for (int k = 0; k < NPASS; ++k) {
        __syncthreads();                       // drains vmcnt -> stage(k) landed
        if (k + 1 < NPASS) stage(k + 1, (k + 1) & 1);   // prefetch under gather

        const float* __restrict__ fbuf = s_f[k & 1];
        const int cbase = k * G;
        #pragma unroll 1
        for (int it = 0; it < GITER; ++it) {
            const int c = cg + 5 * it;
            if (gok && c < G) {
                const float* __restrict__ fb = fbuf + c * SP;
                f4 r;
                #pragma unroll
                for (int j = 0; j < 4; ++j) {
                    const f4 m = md[j];
                    const unsigned pk = __float_as_uint(m.w);
                    const int o0 = (int)(pk & 0xffffu);
                    const int o1 = (int)(pk >> 16);
                    const float hx = 1.0f - m.x;
                    const float t0 = fb[o0], t1 = fb[o0 + 1];   // ds_read2_b32
                    const float u0 = fb[o1], u1 = fb[o1 + 1];
                    r[j] = m.y * (t0 * hx + t1 * m.x) + m.z * (u0 * hx + u1 * m.x);
                }
                __builtin_nontemporal_store(r,
                    (f4*)(out_roi + (size_t)((cbase + c) * NPOS + 4 * q)));
            }
        }
    }
}

extern "C" void kernel_launch(void* const* d_in, const int* in_sizes, int n_in,
                              void* d_out, int out_size, void* d_ws, size_t ws_size,
                              hipStream_t stream)
{
    const float* f0 = (const float*)d_in[0];
    const float* f1 = (const float*)d_in[1];
    const float* f2 = (const float*)d_in[2];
    const float* f3 = (const float*)d_in[3];
    const float* b0 = (const float*)d_in[4];
    const float* b1 = (const float*)d_in[5];
    const float* b2 = (const float*)d_in[6];
    const float* b3 = (const float*)d_in[7];
    float* out = (float*)d_out;

    rroi_align_kernel<<<2048, 256, 0, stream>>>(f0, f1, f2, f3, b0, b1, b2, b3, out);
}

// Round 8
// 491.115 us; speedup vs baseline: 1.1190x; 1.0008x over previous
//
#include <hip/hip_runtime.h>

#define POOLED 14
#define NPOS   196
#define NQUAD  49
#define BUF_N  4096   // floats per buffer; multiple of 256 (KFIX*256 == BUF_N)
#define KFIX   16     // fixed global_load_lds issues per wave per stage

typedef float f4 __attribute__((ext_vector_type(4)));
typedef __attribute__((address_space(1))) const unsigned int guint;
typedef __attribute__((address_space(3))) unsigned int       luint;

// One block per roi. Channel-group passes (G adaptive pow2, G*SP<=BUF_N).
// Staging: async global_load_lds, TRIPLE-buffered with counted vmcnt:
//   iter k: issue stage(k+1) [exactly KFIX loads] -> s_waitcnt vmcnt(KFIX)
//   (= stage(k) landed, stage(k+1) still in flight) -> raw s_barrier ->
//   gather(k). Prefetch latency hides under a full pass instead of being
//   drained at every barrier (T3/T4, 8-phase GEMM technique).
// Buffer safety: stage(k+1) writes buf[(k+1)%3]; its last readers ran
// gather(k-2), which all waves completed before barrier(k-1) < this issue.
__global__ __launch_bounds__(256, 3)
void rroi_align_kernel(const float* __restrict__ f0, const float* __restrict__ f1,
                       const float* __restrict__ f2, const float* __restrict__ f3,
                       const float* __restrict__ b0, const float* __restrict__ b1,
                       const float* __restrict__ b2, const float* __restrict__ b3,
                       float* __restrict__ out)
{
    __shared__ float s_f[3][BUF_N];

    const int blk = blockIdx.x;      // 0..2047 (level*512 + roi)
    const int level = blk >> 9;
    const int roi = blk & 511;
    const int tid = threadIdx.x;

    const float* feat; const float* box; int H, W; float scale;
    switch (level) {
      case 0:  feat = f0; box = b0; H = 200; W = 176; scale = 1.0f;    break;
      case 1:  feat = f1; box = b1; H = 100; W = 88;  scale = 0.5f;    break;
      case 2:  feat = f2; box = b2; H = 50;  W = 44;  scale = 0.25f;   break;
      default: feat = f3; box = b3; H = 25;  W = 22;  scale = 0.125f;  break;
    }
    const int HW = H * W;

    // ---- block-uniform box + clipped bbox (identical math to passing R7) ----
    const float* bp = box + roi * 7;
    const float cx  = (bp[0] * 175.0f / 70.4f + 0.5f) * scale;
    const float cy  = ((bp[1] + 40.0f) * 199.0f / 80.0f + 0.5f) * scale;
    const float rw  = (bp[3] * 175.0f / 70.4f) * scale;
    const float rh  = (bp[4] * 199.0f / 80.0f) * scale;
    const float cth = cosf(bp[6]), sth = sinf(bp[6]);

    const float ex = 0.5f * (fabsf(rw * cth) + fabsf(rh * sth));
    const float ey = 0.5f * (fabsf(rw * sth) + fabsf(rh * cth));
    const int Xlo = min(max((int)floorf(cx - ex), 0), W - 2);
    const int Xhi = min(W - 1, max((int)floorf(cx + ex) + 1, Xlo + 1));
    const int Ylo = min(max((int)floorf(cy - ey), 0), H - 1);
    const int Yhi = min(H - 1, max((int)floorf(cy + ey) + 1, Ylo + 1));
    const int bw = Xhi - Xlo + 1;          // <= 22
    const int bh = Yhi - Ylo + 1;
    const int SP = bw * bh;                // <= 484

    // G = largest pow2 with G*SP <= BUF_N (>=8), clamp 256; NPASS = 256/G
    int Graw = BUF_N / SP;
    int G = 1 << (31 - __clz(Graw));
    if (G > 256) G = 256;
    const int NPASS = 256 / G;
    const int E     = G * SP;              // <= BUF_N
    const int GITER = (G + 4) / 5;

    // magic divisors (exact: els<=4095,SP<=484; rem<=483,bw in [2,23])
    const unsigned M1 = (unsigned)(4294967296.0 / (double)SP) + 1u;  // /SP
    const unsigned M2 = 262144u / (unsigned)bw + 1u;                 // /bw

    const int wbase = tid & 192;           // wave base (0,64,128,192)
    const int lane  = tid & 63;

    // issue EXACTLY KFIX global_load_lds per wave (source clamped; dest linear,
    // KFIX*256 == BUF_N so overshoot writes stay inside the buffer tail)
    auto stage = [&](int pass, int bsel) {
        const float* __restrict__ fp = feat + (size_t)(pass * G) * HW;
        #pragma unroll
        for (int j = 0; j < KFIX; ++j) {
            int els = min(j * 256 + wbase + lane, E - 1);
            int g   = (int)__umulhi((unsigned)els, M1);     // els / SP
            int rem = els - g * SP;
            int ry  = (int)(((unsigned)rem * M2) >> 18);    // rem / bw
            int rx  = rem - ry * bw;
            const float* src = fp + g * HW + (Ylo + ry) * W + (Xlo + rx);
            __builtin_amdgcn_global_load_lds((guint*)src,
                (luint*)&s_f[bsel][j * 256 + wbase], 4, 0, 0);
        }
    };

    // stage(0) early; metadata VALU below hides its latency
    stage(0, 0);

    // ---- per-thread metadata in registers: quad q, positions 4q..4q+3 ----
    const int q  = tid % NQUAD;            // tids>=245 duplicate q, masked below
    const int cg = tid / NQUAD;            // 0..5
    const bool gok = (cg < 5);

    f4 md[4];
    #pragma unroll
    for (int j = 0; j < 4; ++j) {
        const int p  = q * 4 + j;
        const int ph = p / POOLED;
        const int pw = p - ph * POOLED;
        const float fwx = ((float)pw + 0.5f) / (float)POOLED - 0.5f;
        const float fhy = ((float)ph + 0.5f) / (float)POOLED - 0.5f;
        const float lx = fwx * rw;
        const float ly = fhy * rh;
        const float x = cx + lx * cth - ly * sth;
        const float y = cy + lx * sth + ly * cth;

        const bool valid = (y > -1.0f) & (y < (float)H) & (x > -1.0f) & (x < (float)W);
        const float yc = fminf(fmaxf(y, 0.0f), (float)(H - 1));
        const float xc = fminf(fmaxf(x, 0.0f), (float)(W - 1));
        const int y0 = (int)floorf(yc);
        const int x0 = (int)floorf(xc);
        const int y1 = min(y0 + 1, H - 1);
        const float dyw = yc - (float)y0;
        float dxw = xc - (float)x0;

        const float m = valid ? 1.0f : 0.0f;
        const float A = (1.0f - dyw) * m;   // top-row weight
        const float B = dyw * m;            // bottom-row weight

        int xb = x0;
        if (x0 == W - 1) { xb = W - 2; dxw = 1.0f; }   // dup-column border

        const unsigned o0 = (unsigned)((y0 - Ylo) * bw + (xb - Xlo));
        const unsigned o1 = (unsigned)((y1 - Ylo) * bw + (xb - Xlo));
        md[j] = (f4){dxw, A, B, __uint_as_float(o0 | (o1 << 16))};
    }

    float* const out_roi = out + (size_t)blk * (256 * NPOS);

    int bsel = 0;
    #pragma unroll 1
    for (int k = 0; k < NPASS; ++k) {
        const int bnext = (bsel == 2) ? 0 : bsel + 1;
        if (k + 1 < NPASS) {
            stage(k + 1, bnext);
            // stage(k) landed; stage(k+1)'s KFIX loads stay in flight
            asm volatile("s_waitcnt vmcnt(16)" ::: "memory");
        } else {
            asm volatile("s_waitcnt vmcnt(0)" ::: "memory");
        }
        __builtin_amdgcn_s_barrier();
        asm volatile("" ::: "memory");     // no LDS reads hoisted above barrier

        const float* __restrict__ fbuf = s_f[bsel];
        const int cbase = k * G;
        #pragma unroll 1
        for (int it = 0; it < GITER; ++it) {
            const int c = cg + 5 * it;
            if (gok && c < G) {
                const float* __restrict__ fb = fbuf + c * SP;
                f4 r;
                #pragma unroll
                for (int j = 0; j < 4; ++j) {
                    const f4 m = md[j];
                    const unsigned pk = __float_as_uint(m.w);
                    const int o0 = (int)(pk & 0xffffu);
                    const int o1 = (int)(pk >> 16);
                    const float hx = 1.0f - m.x;
                    const float t0 = fb[o0], t1 = fb[o0 + 1];   // ds_read2_b32
                    const float u0 = fb[o1], u1 = fb[o1 + 1];
                    r[j] = m.y * (t0 * hx + t1 * m.x) + m.z * (u0 * hx + u1 * m.x);
                }
                __builtin_nontemporal_store(r,
                    (f4*)(out_roi + (size_t)((cbase + c) * NPOS + 4 * q)));
            }
        }
        bsel = bnext;
    }
}

extern "C" void kernel_launch(void* const* d_in, const int* in_sizes, int n_in,
                              void* d_out, int out_size, void* d_ws, size_t ws_size,
                              hipStream_t stream)
{
    const float* f0 = (const float*)d_in[0];
    const float* f1 = (const float*)d_in[1];
    const float* f2 = (const float*)d_in[2];
    const float* f3 = (const float*)d_in[3];
    const float* b0 = (const float*)d_in[4];
    const float* b1 = (const float*)d_in[5];
    const float* b2 = (const float*)d_in[6];
    const float* b3 = (const float*)d_in[7];
    float* out = (float*)d_out;

    rroi_align_kernel<<<2048, 256, 0, stream>>>(f0, f1, f2, f3, b0, b1, b2, b3, out);
}